// Round 11
// baseline (227.887 us; speedup 1.0000x reference)
//
#include <hip/hip_runtime.h>
#include <math.h>

#define NN 10000
#define NE 160000
#define NRBF 50
#define WNUM 2304
#define EPSV 1e-5f

#define A_P1 0.125f
#define A_P2 0.17677669529663687f
#define A_P3 0.125f
#define A_P4 0.17677669529663687f
#define INV_SQRT3 0.5773502691896258f
#define INV_SQRT_M0 0.17677669529663687f
#define INV_SQRT_M1 0.25f

typedef __attribute__((ext_vector_type(8))) short bf16x8;
typedef __attribute__((ext_vector_type(4))) float f32x4;
typedef __attribute__((ext_vector_type(4))) int i32x4;

#define MFMA16(a, b, c) __builtin_amdgcn_mfma_f32_16x16x32_bf16(a, b, c, 0, 0, 0)

__device__ __forceinline__ short f2bf(float x) {
  unsigned u = __float_as_uint(x);
  unsigned r = (u + 0x7fffu + ((u >> 16) & 1u)) >> 16;
  return (short)r;
}

// ---- weight prep: transpose + bf16 + fragment-order packing ----
// Per 16-col tile t: 1024 shorts = [chunk(2)][lane(64)][kk(8)].
__global__ void prep_weights(const float* __restrict__ W1, const float* __restrict__ W2,
                             const float* __restrict__ W3, short* __restrict__ W1P,
                             short* __restrict__ W2P, short* __restrict__ W3P) {
  int s = blockIdx.x * 256 + threadIdx.x;
  if (s < WNUM * 64) {
    int t = s >> 10, r = s & 1023;
    int ch = r >> 9, l = (r >> 3) & 63, kk = r & 7;
    int row = t * 16 + (l & 15);
    int k = ((l >> 4) << 3) + (ch << 5) + kk;
    W3P[s] = f2bf(W3[k * WNUM + row]);
  } else if (s < WNUM * 64 + 4096) {
    int s2 = s - WNUM * 64;
    int t = s2 >> 10, r = s2 & 1023;
    int ch = r >> 9, l = (r >> 3) & 63, kk = r & 7;
    int row = t * 16 + (l & 15);
    int k = ((l >> 4) << 3) + (ch << 5) + kk;
    W1P[s2] = f2bf(k < NRBF ? W1[k * 64 + row] : 0.f);
  } else if (s < WNUM * 64 + 8192) {
    int s2 = s - WNUM * 64 - 4096;
    int t = s2 >> 10, r = s2 & 1023;
    int ch = r >> 9, l = (r >> 3) & 63, kk = r & 7;
    int row = t * 16 + (l & 15);
    int k = ((l >> 4) << 3) + (ch << 5) + kk;
    W2P[s2] = f2bf(W2[k * 64 + row]);
  }
}

__global__ __launch_bounds__(256, 3) void edge_kernel(
    const float* __restrict__ h, const int* __restrict__ eidx,
    const float* __restrict__ esh, const float* __restrict__ ef,
    const short* __restrict__ W1P, const float* __restrict__ b1,
    const short* __restrict__ W2P, const float* __restrict__ b2,
    const short* __restrict__ W3P, const float* __restrict__ b3,
    float* __restrict__ agg, float* __restrict__ cnt) {
  __shared__ short act[64 * 72];   // ef -> h1 -> h2, in-place MLP (9216 B)
  // coef (24 KB f32): s0c[0..2047]=0.125*s0[u] (serves w1 AND w3);
  // w2c x/y/z at 2048/3072/4096 (+u*64) = A_P2*s1[u][i] (y0 at finalize);
  // d4c[5120..6143]=A_P4/sqrt3*(s1.y1). Reused as reduce scratch after phase C.
  __shared__ float coef[6144];
  __shared__ float y0s[64], y1s[192];
  __shared__ float b1s[64], b2s[64];
  __shared__ int dsts[64];
  float* scratch = coef;

  const int tid = threadIdx.x;
  const int e0 = blockIdx.x * 64;

  // ---- Phase A: staging ----
  for (int idx = tid; idx < 64 * 64; idx += 256) {
    int e = idx >> 6, k = idx & 63;
    float v = (k < NRBF) ? ef[(long)(e0 + e) * NRBF + k] : 0.f;
    act[e * 72 + k] = f2bf(v);
  }
  if (tid < 64) { b1s[tid] = b1[tid]; b2s[tid] = b2[tid]; }
  {
    int e = tid >> 2, q = tid & 3;
    int ge = e0 + e;
    int src = eidx[ge];
    float y0 = esh[ge * 4 + 0];
    float y1x = esh[ge * 4 + 1], y1y = esh[ge * 4 + 2], y1z = esh[ge * 4 + 3];
    const float* hs = h + (long)src * 80;
    for (int u = q; u < 32; u += 4) coef[u * 64 + e] = 0.125f * hs[u];
    for (int u = q; u < 16; u += 4) {
      float sx = hs[32 + u * 3], sy = hs[33 + u * 3], sz = hs[34 + u * 3];
      coef[2048 + u * 64 + e] = A_P2 * sx;
      coef[3072 + u * 64 + e] = A_P2 * sy;
      coef[4096 + u * 64 + e] = A_P2 * sz;
      coef[5120 + u * 64 + e] = A_P4 * INV_SQRT3 * (sx * y1x + sy * y1y + sz * y1z);
    }
    if (q == 0) {
      y0s[e] = y0;
      y1s[e] = y1x; y1s[64 + e] = y1y; y1s[128 + e] = y1z;
      dsts[e] = eidx[NE + ge];
    }
  }
  __syncthreads();

  const int wid = tid >> 6, l = tid & 63;
  const int lr = l & 15, lg = l >> 4;
  const int g16 = lg * 4;
  const int er = wid * 16;

  // ---- MLP layer 1 (in place; rows wave-private, no barrier after) ----
  {
    bf16x8 a0 = *(const bf16x8*)&act[(er + lr) * 72 + lg * 8];
    bf16x8 a1 = *(const bf16x8*)&act[(er + lr) * 72 + 32 + lg * 8];
#pragma unroll
    for (int jt = 0; jt < 4; ++jt) {
      const short* wb = W1P + (jt << 10) + (l << 3);
      bf16x8 b0 = *(const bf16x8*)wb;
      bf16x8 b1f = *(const bf16x8*)(wb + 512);
      float bias = b1s[jt * 16 + lr];
      f32x4 d = {bias, bias, bias, bias};
      d = MFMA16(a0, b0, d);
      d = MFMA16(a1, b1f, d);
#pragma unroll
      for (int r = 0; r < 4; ++r) {
        float x = d[r];
        x = x / (1.f + __expf(-x));
        act[(er + lg * 4 + r) * 72 + jt * 16 + lr] = f2bf(x);
      }
    }
  }
  // ---- MLP layer 2 (in place) ----
  {
    bf16x8 a0 = *(const bf16x8*)&act[(er + lr) * 72 + lg * 8];
    bf16x8 a1 = *(const bf16x8*)&act[(er + lr) * 72 + 32 + lg * 8];
#pragma unroll
    for (int jt = 0; jt < 4; ++jt) {
      const short* wb = W2P + (jt << 10) + (l << 3);
      bf16x8 b0 = *(const bf16x8*)wb;
      bf16x8 b1f = *(const bf16x8*)(wb + 512);
      float bias = b2s[jt * 16 + lr];
      f32x4 d = {bias, bias, bias, bias};
      d = MFMA16(a0, b0, d);
      d = MFMA16(a1, b1f, d);
#pragma unroll
      for (int r = 0; r < 4; ++r) {
        float x = d[r];
        x = x / (1.f + __expf(-x));
        act[(er + lg * 4 + r) * 72 + jt * 16 + lr] = f2bf(x);
      }
    }
  }
  __syncthreads();

  // ---- Phase C: region-split waves; each wave = all 4 edge-groups ----
  bf16x8 a0g[4], a1g[4];
#pragma unroll
  for (int g = 0; g < 4; ++g) {
    a0g[g] = *(const bf16x8*)&act[(g * 16 + lr) * 72 + lg * 8];
    a1g[g] = *(const bf16x8*)&act[(g * 16 + lr) * 72 + 32 + lg * 8];
  }

// tile-pair fold for m0-style regions: even tile -> acc0, odd -> acc1
#define M0_PAIR(TE, COFF)                                            \
  {                                                                  \
    const short* wbE = W3P + ((TE) << 10) + (l << 3);                \
    const short* wbO = W3P + (((TE) + 1) << 10) + (l << 3);          \
    bf16x8 E0 = *(const bf16x8*)wbE;                                 \
    bf16x8 E1 = *(const bf16x8*)(wbE + 512);                         \
    bf16x8 O0 = *(const bf16x8*)wbO;                                 \
    bf16x8 O1 = *(const bf16x8*)(wbO + 512);                         \
    float be = b3[((TE) << 4) + lr];                                 \
    float bo = b3[(((TE) + 1) << 4) + lr];                           \
    _Pragma("unroll")                                                \
    for (int g = 0; g < 4; ++g) {                                    \
      f32x4 c = *(const f32x4*)&coef[(COFF) + g * 16 + g16];         \
      f32x4 d = {be, be, be, be};                                    \
      d = MFMA16(a0g[g], E0, d);                                     \
      f32x4 v = MFMA16(a1g[g], E1, d);                               \
      f32x4 d2 = {bo, bo, bo, bo};                                   \
      d2 = MFMA16(a0g[g], O0, d2);                                   \
      f32x4 v2 = MFMA16(a1g[g], O1, d2);                             \
      _Pragma("unroll")                                              \
      for (int r = 0; r < 4; ++r) {                                  \
        acc0[g][r] += c[r] * v[r];                                   \
        acc1[g][r] += c[r] * v2[r];                                  \
      }                                                              \
    }                                                                \
  }

#define W2_TILE(U)                                                   \
  {                                                                  \
    const short* wb = W3P + ((64 + (U)) << 10) + (l << 3);           \
    bf16x8 B0 = *(const bf16x8*)wb;                                  \
    bf16x8 B1 = *(const bf16x8*)(wb + 512);                          \
    float bb = b3[((64 + (U)) << 4) + lr];                           \
    _Pragma("unroll")                                                \
    for (int g = 0; g < 4; ++g) {                                    \
      f32x4 d = {bb, bb, bb, bb};                                    \
      d = MFMA16(a0g[g], B0, d);                                     \
      f32x4 v = MFMA16(a1g[g], B1, d);                               \
      f32x4 cx = *(const f32x4*)&coef[2048 + (U) * 64 + g * 16 + g16]; \
      f32x4 cy = *(const f32x4*)&coef[3072 + (U) * 64 + g * 16 + g16]; \
      f32x4 cz = *(const f32x4*)&coef[4096 + (U) * 64 + g * 16 + g16]; \
      _Pragma("unroll")                                              \
      for (int r = 0; r < 4; ++r) {                                  \
        mx[g][r] += cx[r] * v[r];                                    \
        my[g][r] += cy[r] * v[r];                                    \
        mz[g][r] += cz[r] * v[r];                                    \
      }                                                              \
    }                                                                \
  }

#define W3_TILE(U)                                                   \
  {                                                                  \
    const short* wb = W3P + ((80 + (U)) << 10) + (l << 3);           \
    bf16x8 B0 = *(const bf16x8*)wb;                                  \
    bf16x8 B1 = *(const bf16x8*)(wb + 512);                          \
    float bb = b3[((80 + (U)) << 4) + lr];                           \
    _Pragma("unroll")                                                \
    for (int g = 0; g < 4; ++g) {                                    \
      f32x4 d = {bb, bb, bb, bb};                                    \
      d = MFMA16(a0g[g], B0, d);                                     \
      f32x4 v = MFMA16(a1g[g], B1, d);                               \
      f32x4 c = *(const f32x4*)&coef[(U) * 64 + g * 16 + g16];       \
      _Pragma("unroll")                                              \
      for (int r = 0; r < 4; ++r) t3[g][r] += c[r] * v[r];           \
    }                                                                \
  }

  if (wid < 2) {
    // ---- m0 waves ----
    f32x4 acc0[4], acc1[4];
#pragma unroll
    for (int g = 0; g < 4; ++g) {
      acc0[g] = (f32x4){0, 0, 0, 0};
      acc1[g] = (f32x4){0, 0, 0, 0};
    }
    if (wid == 0) {
#pragma unroll 2
      for (int u = 0; u < 24; ++u) M0_PAIR(2 * u, u * 64);
#pragma unroll
      for (int g = 0; g < 4; ++g) {
        f32x4 y0v = *(const f32x4*)&y0s[g * 16 + g16];
#pragma unroll
        for (int r = 0; r < 4; ++r) { acc0[g][r] *= y0v[r]; acc1[g][r] *= y0v[r]; }
      }
    } else {
#pragma unroll 2
      for (int u = 24; u < 32; ++u) M0_PAIR(2 * u, u * 64);
#pragma unroll
      for (int g = 0; g < 4; ++g) {
        f32x4 y0v = *(const f32x4*)&y0s[g * 16 + g16];
#pragma unroll
        for (int r = 0; r < 4; ++r) { acc0[g][r] *= y0v[r]; acc1[g][r] *= y0v[r]; }
      }
#pragma unroll 2
      for (int p = 0; p < 16; ++p) M0_PAIR(112 + 2 * p, 5120 + p * 64);
    }
    // exchange: wid1 gives g0,g1 ; wid0 gives g2,g3
    __syncthreads();
    if (wid == 1) {
      float* p = scratch + l * 20;
      *(f32x4*)(p + 0) = acc0[0]; *(f32x4*)(p + 4) = acc1[0];
      *(f32x4*)(p + 8) = acc0[1]; *(f32x4*)(p + 12) = acc1[1];
    } else {
      float* p = scratch + 1280 + l * 20;
      *(f32x4*)(p + 0) = acc0[2]; *(f32x4*)(p + 4) = acc1[2];
      *(f32x4*)(p + 8) = acc0[3]; *(f32x4*)(p + 12) = acc1[3];
    }
    __syncthreads();
    const int gb = (wid == 0) ? 0 : 2;
    const float* p = (wid == 0) ? (scratch + l * 20) : (scratch + 1280 + l * 20);
    f32x4 t0 = *(const f32x4*)(p + 0), t1 = *(const f32x4*)(p + 4);
    f32x4 t2 = *(const f32x4*)(p + 8), t3_ = *(const f32x4*)(p + 12);
    i32x4 dd0 = *(const i32x4*)&dsts[(gb + 0) * 16 + g16];
    i32x4 dd1 = *(const i32x4*)&dsts[(gb + 1) * 16 + g16];
#pragma unroll
    for (int r = 0; r < 4; ++r) {
      float* base = agg + (long)dd0[r] * 80;
      atomicAdd(base + lr, acc0[gb + 0][r] + t0[r]);
      atomicAdd(base + 16 + lr, acc1[gb + 0][r] + t1[r]);
    }
#pragma unroll
    for (int r = 0; r < 4; ++r) {
      float* base = agg + (long)dd1[r] * 80;
      atomicAdd(base + lr, acc0[gb + 1][r] + t2[r]);
      atomicAdd(base + 16 + lr, acc1[gb + 1][r] + t3_[r]);
    }
  } else {
    // ---- m1 waves ----
    f32x4 mx[4], my[4], mz[4], t3[4];
#pragma unroll
    for (int g = 0; g < 4; ++g) {
      mx[g] = (f32x4){0, 0, 0, 0}; my[g] = (f32x4){0, 0, 0, 0};
      mz[g] = (f32x4){0, 0, 0, 0}; t3[g] = (f32x4){0, 0, 0, 0};
    }
    if (wid == 2) {
#pragma unroll 2
      for (int u = 0; u < 8; ++u) W2_TILE(u);
#pragma unroll 2
      for (int u = 0; u < 16; ++u) W3_TILE(u);
    } else {
#pragma unroll 2
      for (int u = 8; u < 16; ++u) W2_TILE(u);
#pragma unroll 2
      for (int u = 16; u < 32; ++u) W3_TILE(u);
    }
    // finalize: m = y0*m(w2) + y1*t3(w3)
#pragma unroll
    for (int g = 0; g < 4; ++g) {
      f32x4 y0v = *(const f32x4*)&y0s[g * 16 + g16];
      f32x4 yx = *(const f32x4*)&y1s[g * 16 + g16];
      f32x4 yy = *(const f32x4*)&y1s[64 + g * 16 + g16];
      f32x4 yz = *(const f32x4*)&y1s[128 + g * 16 + g16];
#pragma unroll
      for (int r = 0; r < 4; ++r) {
        mx[g][r] = mx[g][r] * y0v[r] + yx[r] * t3[g][r];
        my[g][r] = my[g][r] * y0v[r] + yy[r] * t3[g][r];
        mz[g][r] = mz[g][r] * y0v[r] + yz[r] * t3[g][r];
      }
    }
    // exchange: wid3 gives g0,g1 ; wid2 gives g2,g3
    __syncthreads();
    if (wid == 3) {
      float* p = scratch + 2560 + l * 28;
      *(f32x4*)(p + 0) = mx[0]; *(f32x4*)(p + 4) = my[0]; *(f32x4*)(p + 8) = mz[0];
      *(f32x4*)(p + 12) = mx[1]; *(f32x4*)(p + 16) = my[1]; *(f32x4*)(p + 20) = mz[1];
    } else {
      float* p = scratch + 4352 + l * 28;
      *(f32x4*)(p + 0) = mx[2]; *(f32x4*)(p + 4) = my[2]; *(f32x4*)(p + 8) = mz[2];
      *(f32x4*)(p + 12) = mx[3]; *(f32x4*)(p + 16) = my[3]; *(f32x4*)(p + 20) = mz[3];
    }
    __syncthreads();
    const int gb = (wid == 2) ? 0 : 2;
    const float* p = (wid == 2) ? (scratch + 2560 + l * 28) : (scratch + 4352 + l * 28);
    f32x4 u0 = *(const f32x4*)(p + 0), u1 = *(const f32x4*)(p + 4);
    f32x4 u2 = *(const f32x4*)(p + 8), u3 = *(const f32x4*)(p + 12);
    f32x4 u4 = *(const f32x4*)(p + 16), u5 = *(const f32x4*)(p + 20);
    i32x4 dd0 = *(const i32x4*)&dsts[(gb + 0) * 16 + g16];
    i32x4 dd1 = *(const i32x4*)&dsts[(gb + 1) * 16 + g16];
#pragma unroll
    for (int r = 0; r < 4; ++r) {
      float* base = agg + (long)dd0[r] * 80;
      atomicAdd(base + 32 + lr * 3 + 0, mx[gb + 0][r] + u0[r]);
      atomicAdd(base + 32 + lr * 3 + 1, my[gb + 0][r] + u1[r]);
      atomicAdd(base + 32 + lr * 3 + 2, mz[gb + 0][r] + u2[r]);
    }
#pragma unroll
    for (int r = 0; r < 4; ++r) {
      float* base = agg + (long)dd1[r] * 80;
      atomicAdd(base + 32 + lr * 3 + 0, mx[gb + 1][r] + u3[r]);
      atomicAdd(base + 32 + lr * 3 + 1, my[gb + 1][r] + u4[r]);
      atomicAdd(base + 32 + lr * 3 + 2, mz[gb + 1][r] + u5[r]);
    }
  }
  if (tid < 64) atomicAdd(cnt + dsts[tid], 1.0f);
#undef M0_PAIR
#undef W2_TILE
#undef W3_TILE
}

__global__ __launch_bounds__(256) void node_a(
    const float* __restrict__ h, const float* __restrict__ A0,
    const float* __restrict__ A1p, const float* __restrict__ agg,
    const float* __restrict__ cnt, float* __restrict__ outpre,
    float* __restrict__ stats) {
  __shared__ float redw[4][80];
  const int tid = threadIdx.x;
  const int wid = tid >> 6, l = tid & 63;
  const int n = blockIdx.x * 256 + tid;
  float x0[32], x1[48];
#pragma unroll
  for (int w = 0; w < 32; w++) x0[w] = 0.f;
#pragma unroll
  for (int c = 0; c < 48; c++) x1[c] = 0.f;
  if (n < NN) {
    const float* hr = h + (long)n * 80;
    const float* ar = agg + (long)n * 80;
    float inv = 1.f / fmaxf(cnt[n], 1.f);
#pragma unroll 1
    for (int u = 0; u < 32; u++) {
      float hu = hr[u];
#pragma unroll
      for (int w = 0; w < 32; w++) x0[w] += hu * A0[u * 32 + w];
    }
#pragma unroll
    for (int w = 0; w < 32; w++) x0[w] = x0[w] * INV_SQRT_M0 + ar[w] * inv;
#pragma unroll 1
    for (int u = 0; u < 16; u++) {
      float a = hr[32 + u * 3], b_ = hr[33 + u * 3], c_ = hr[34 + u * 3];
#pragma unroll
      for (int w = 0; w < 16; w++) {
        float Aw = A1p[u * 16 + w];
        x1[w * 3 + 0] += a * Aw;
        x1[w * 3 + 1] += b_ * Aw;
        x1[w * 3 + 2] += c_ * Aw;
      }
    }
#pragma unroll
    for (int c = 0; c < 48; c++) x1[c] = x1[c] * INV_SQRT_M1 + ar[32 + c] * inv;
    float* opr = outpre + (long)n * 80;
#pragma unroll
    for (int w = 0; w < 32; w++) opr[w] = x0[w];
#pragma unroll
    for (int c = 0; c < 48; c++) opr[32 + c] = x1[c];
  }
#pragma unroll 1
  for (int c = 0; c < 32; ++c) {
    float s = x0[c];
#pragma unroll
    for (int m = 32; m >= 1; m >>= 1) s += __shfl_xor(s, m, 64);
    if (l == 0) redw[wid][c] = s;
  }
#pragma unroll 1
  for (int c = 0; c < 32; ++c) {
    float v = x0[c];
    float s = v * v;
#pragma unroll
    for (int m = 32; m >= 1; m >>= 1) s += __shfl_xor(s, m, 64);
    if (l == 0) redw[wid][32 + c] = s;
  }
#pragma unroll 1
  for (int u = 0; u < 16; ++u) {
    float s = x1[u * 3] * x1[u * 3] + x1[u * 3 + 1] * x1[u * 3 + 1] +
              x1[u * 3 + 2] * x1[u * 3 + 2];
#pragma unroll
    for (int m = 32; m >= 1; m >>= 1) s += __shfl_xor(s, m, 64);
    if (l == 0) redw[wid][64 + u] = s;
  }
  __syncthreads();
  if (tid < 80)
    atomicAdd(&stats[tid],
              redw[0][tid] + redw[1][tid] + redw[2][tid] + redw[3][tid]);
}

__global__ void node_b(const float* __restrict__ outpre, const float* __restrict__ stats,
                       const float* __restrict__ bnw0, const float* __restrict__ bnb0,
                       const float* __restrict__ bnw1, const float* __restrict__ h,
                       float* __restrict__ out) {
  int idx = blockIdx.x * 256 + threadIdx.x;
  if (idx >= NN * 80) return;
  int c = idx % 80;
  float v = outpre[idx];
  const float invN = 1.f / NN;
  float o;
  if (c < 32) {
    float mu = stats[c] * invN;
    float var = stats[32 + c] * invN - mu * mu;
    o = (v - mu) * rsqrtf(var + EPSV) * bnw0[c] + bnb0[c];
  } else {
    int u = (c - 32) / 3;
    float nr = stats[64 + u] * invN;
    o = v * rsqrtf(nr + EPSV) * bnw1[u];
  }
  out[idx] = o + h[idx];
}

extern "C" void kernel_launch(void* const* d_in, const int* in_sizes, int n_in,
                              void* d_out, int out_size, void* d_ws, size_t ws_size,
                              hipStream_t stream) {
  const float* h    = (const float*)d_in[0];
  const int*   eidx = (const int*)d_in[1];
  const float* esh  = (const float*)d_in[2];
  const float* ef   = (const float*)d_in[3];
  const float* W1   = (const float*)d_in[4];
  const float* b1   = (const float*)d_in[5];
  const float* W2   = (const float*)d_in[6];
  const float* b2   = (const float*)d_in[7];
  const float* W3   = (const float*)d_in[8];
  const float* b3   = (const float*)d_in[9];
  const float* A0   = (const float*)d_in[10];
  const float* A1p  = (const float*)d_in[11];
  const float* bnw0 = (const float*)d_in[12];
  const float* bnb0 = (const float*)d_in[13];
  const float* bnw1 = (const float*)d_in[14];
  float* out = (float*)d_out;

  float* ws = (float*)d_ws;
  float* agg    = ws;             // 800000
  float* cnt    = ws + 800000;    // 10000
  float* stats  = ws + 810000;    // 80
  float* outpre = ws + 810080;    // 800000
  short* W3P    = (short*)(ws + 1610080);  // 147456 shorts
  short* W1P    = W3P + WNUM * 64;         // 4096 shorts
  short* W2P    = W1P + 4096;              // 4096 shorts

  hipMemsetAsync(agg, 0, (size_t)810080 * sizeof(float), stream);

  prep_weights<<<(WNUM * 64 + 8192 + 255) / 256, 256, 0, stream>>>(W1, W2, W3, W1P,
                                                                   W2P, W3P);
  edge_kernel<<<NE / 64, 256, 0, stream>>>(h, eidx, esh, ef, W1P, b1, W2P, b2, W3P, b3,
                                           agg, cnt);
  node_a<<<(NN + 255) / 256, 256, 0, stream>>>(h, A0, A1p, agg, cnt, outpre, stats);
  node_b<<<(NN * 80 + 255) / 256, 256, 0, stream>>>(outpre, stats, bnw0, bnb0, bnw1, h,
                                                    out);
}

// Round 12
// 202.891 us; speedup vs baseline: 1.1232x; 1.1232x over previous
//
#include <hip/hip_runtime.h>
#include <math.h>

#define NN 10000
#define NE 160000
#define NRBF 50
#define WNUM 2304
#define EPSV 1e-5f

#define A_P1 0.125f
#define A_P2 0.17677669529663687f
#define A_P3 0.125f
#define A_P4 0.17677669529663687f
#define INV_SQRT3 0.5773502691896258f
#define INV_SQRT_M0 0.17677669529663687f
#define INV_SQRT_M1 0.25f

typedef __attribute__((ext_vector_type(8))) short bf16x8;
typedef __attribute__((ext_vector_type(4))) float f32x4;
typedef __attribute__((ext_vector_type(4))) int i32x4;

#define MFMA16(a, b, c) __builtin_amdgcn_mfma_f32_16x16x32_bf16(a, b, c, 0, 0, 0)

__device__ __forceinline__ short f2bf(float x) {
  unsigned u = __float_as_uint(x);
  unsigned r = (u + 0x7fffu + ((u >> 16) & 1u)) >> 16;
  return (short)r;
}

// ---- weight prep: transpose + bf16 + fragment-order packing ----
// Per 16-col tile t: 1024 shorts = [chunk(2)][lane(64)][kk(8)].
__global__ void prep_weights(const float* __restrict__ W1, const float* __restrict__ W2,
                             const float* __restrict__ W3, short* __restrict__ W1P,
                             short* __restrict__ W2P, short* __restrict__ W3P) {
  int s = blockIdx.x * 256 + threadIdx.x;
  if (s < WNUM * 64) {
    int t = s >> 10, r = s & 1023;
    int ch = r >> 9, l = (r >> 3) & 63, kk = r & 7;
    int row = t * 16 + (l & 15);
    int k = ((l >> 4) << 3) + (ch << 5) + kk;
    W3P[s] = f2bf(W3[k * WNUM + row]);
  } else if (s < WNUM * 64 + 4096) {
    int s2 = s - WNUM * 64;
    int t = s2 >> 10, r = s2 & 1023;
    int ch = r >> 9, l = (r >> 3) & 63, kk = r & 7;
    int row = t * 16 + (l & 15);
    int k = ((l >> 4) << 3) + (ch << 5) + kk;
    W1P[s2] = f2bf(k < NRBF ? W1[k * 64 + row] : 0.f);
  } else if (s < WNUM * 64 + 8192) {
    int s2 = s - WNUM * 64 - 4096;
    int t = s2 >> 10, r = s2 & 1023;
    int ch = r >> 9, l = (r >> 3) & 63, kk = r & 7;
    int row = t * 16 + (l & 15);
    int k = ((l >> 4) << 3) + (ch << 5) + kk;
    W2P[s2] = f2bf(W2[k * 64 + row]);
  }
}

__global__ __launch_bounds__(256, 3) void edge_kernel(
    const float* __restrict__ h, const int* __restrict__ eidx,
    const float* __restrict__ esh, const float* __restrict__ ef,
    const short* __restrict__ W1P, const float* __restrict__ b1,
    const short* __restrict__ W2P, const float* __restrict__ b2,
    const short* __restrict__ W3P, const float* __restrict__ b3,
    float* __restrict__ agg, float* __restrict__ cnt) {
  __shared__ short act[64 * 72];   // ef -> h1 -> h2, in-place MLP (9216 B)
  // coef (24 KB f32): s0c[0..2047]=0.125*s0[u] (serves w1 AND w3);
  // w2c x/y/z at 2048/3072/4096 (+u*64) = A_P2*s1[u][i] (y0 at finalize);
  // d4c[5120..6143]=A_P4/sqrt3*(s1.y1). Reused as reduce scratch after phase C.
  __shared__ float coef[6144];
  __shared__ float y0s[64], y1s[192];
  __shared__ float b1s[64], b2s[64];
  __shared__ int dsts[64];
  float* scratch = coef;

  const int tid = threadIdx.x;
  const int e0 = blockIdx.x * 64;

  // ---- Phase A: staging ----
  for (int idx = tid; idx < 64 * 64; idx += 256) {
    int e = idx >> 6, k = idx & 63;
    float v = (k < NRBF) ? ef[(long)(e0 + e) * NRBF + k] : 0.f;
    act[e * 72 + k] = f2bf(v);
  }
  if (tid < 64) { b1s[tid] = b1[tid]; b2s[tid] = b2[tid]; }
  {
    int e = tid >> 2, q = tid & 3;
    int ge = e0 + e;
    int src = eidx[ge];
    float y0 = esh[ge * 4 + 0];
    float y1x = esh[ge * 4 + 1], y1y = esh[ge * 4 + 2], y1z = esh[ge * 4 + 3];
    const float* hs = h + (long)src * 80;
    for (int u = q; u < 32; u += 4) coef[u * 64 + e] = 0.125f * hs[u];
    for (int u = q; u < 16; u += 4) {
      float sx = hs[32 + u * 3], sy = hs[33 + u * 3], sz = hs[34 + u * 3];
      coef[2048 + u * 64 + e] = A_P2 * sx;
      coef[3072 + u * 64 + e] = A_P2 * sy;
      coef[4096 + u * 64 + e] = A_P2 * sz;
      coef[5120 + u * 64 + e] = A_P4 * INV_SQRT3 * (sx * y1x + sy * y1y + sz * y1z);
    }
    if (q == 0) {
      y0s[e] = y0;
      y1s[e] = y1x; y1s[64 + e] = y1y; y1s[128 + e] = y1z;
      dsts[e] = eidx[NE + ge];
    }
  }
  __syncthreads();

  const int wid = tid >> 6, l = tid & 63;
  const int lr = l & 15, lg = l >> 4;
  const int g16 = lg * 4;
  const int er = wid * 16;

  // ---- MLP layer 1 (in place; rows wave-private, no barrier after) ----
  {
    bf16x8 a0 = *(const bf16x8*)&act[(er + lr) * 72 + lg * 8];
    bf16x8 a1 = *(const bf16x8*)&act[(er + lr) * 72 + 32 + lg * 8];
#pragma unroll
    for (int jt = 0; jt < 4; ++jt) {
      const short* wb = W1P + (jt << 10) + (l << 3);
      bf16x8 b0 = *(const bf16x8*)wb;
      bf16x8 b1f = *(const bf16x8*)(wb + 512);
      float bias = b1s[jt * 16 + lr];
      f32x4 d = {bias, bias, bias, bias};
      d = MFMA16(a0, b0, d);
      d = MFMA16(a1, b1f, d);
#pragma unroll
      for (int r = 0; r < 4; ++r) {
        float x = d[r];
        x = x / (1.f + __expf(-x));
        act[(er + lg * 4 + r) * 72 + jt * 16 + lr] = f2bf(x);
      }
    }
  }
  // ---- MLP layer 2 (in place) ----
  {
    bf16x8 a0 = *(const bf16x8*)&act[(er + lr) * 72 + lg * 8];
    bf16x8 a1 = *(const bf16x8*)&act[(er + lr) * 72 + 32 + lg * 8];
#pragma unroll
    for (int jt = 0; jt < 4; ++jt) {
      const short* wb = W2P + (jt << 10) + (l << 3);
      bf16x8 b0 = *(const bf16x8*)wb;
      bf16x8 b1f = *(const bf16x8*)(wb + 512);
      float bias = b2s[jt * 16 + lr];
      f32x4 d = {bias, bias, bias, bias};
      d = MFMA16(a0, b0, d);
      d = MFMA16(a1, b1f, d);
#pragma unroll
      for (int r = 0; r < 4; ++r) {
        float x = d[r];
        x = x / (1.f + __expf(-x));
        act[(er + lg * 4 + r) * 72 + jt * 16 + lr] = f2bf(x);
      }
    }
  }
  __syncthreads();

  // ---- Phase C: region-split waves; each wave = all 4 edge-groups ----
  bf16x8 a0g[4], a1g[4];
#pragma unroll
  for (int g = 0; g < 4; ++g) {
    a0g[g] = *(const bf16x8*)&act[(g * 16 + lr) * 72 + lg * 8];
    a1g[g] = *(const bf16x8*)&act[(g * 16 + lr) * 72 + 32 + lg * 8];
  }

// tile-pair fold for m0-style regions: even tile -> acc0, odd -> acc1
#define M0_PAIR(TE, COFF)                                            \
  {                                                                  \
    const short* wbE = W3P + ((TE) << 10) + (l << 3);                \
    const short* wbO = W3P + (((TE) + 1) << 10) + (l << 3);          \
    bf16x8 E0 = *(const bf16x8*)wbE;                                 \
    bf16x8 E1 = *(const bf16x8*)(wbE + 512);                         \
    bf16x8 O0 = *(const bf16x8*)wbO;                                 \
    bf16x8 O1 = *(const bf16x8*)(wbO + 512);                         \
    float be = b3[((TE) << 4) + lr];                                 \
    float bo = b3[(((TE) + 1) << 4) + lr];                           \
    _Pragma("unroll")                                                \
    for (int g = 0; g < 4; ++g) {                                    \
      f32x4 c = *(const f32x4*)&coef[(COFF) + g * 16 + g16];         \
      f32x4 d = {be, be, be, be};                                    \
      d = MFMA16(a0g[g], E0, d);                                     \
      f32x4 v = MFMA16(a1g[g], E1, d);                               \
      f32x4 d2 = {bo, bo, bo, bo};                                   \
      d2 = MFMA16(a0g[g], O0, d2);                                   \
      f32x4 v2 = MFMA16(a1g[g], O1, d2);                             \
      _Pragma("unroll")                                              \
      for (int r = 0; r < 4; ++r) {                                  \
        acc0[g][r] += c[r] * v[r];                                   \
        acc1[g][r] += c[r] * v2[r];                                  \
      }                                                              \
    }                                                                \
  }

#define W2_TILE(U)                                                   \
  {                                                                  \
    const short* wb = W3P + ((64 + (U)) << 10) + (l << 3);           \
    bf16x8 B0 = *(const bf16x8*)wb;                                  \
    bf16x8 B1 = *(const bf16x8*)(wb + 512);                          \
    float bb = b3[((64 + (U)) << 4) + lr];                           \
    _Pragma("unroll")                                                \
    for (int g = 0; g < 4; ++g) {                                    \
      f32x4 d = {bb, bb, bb, bb};                                    \
      d = MFMA16(a0g[g], B0, d);                                     \
      f32x4 v = MFMA16(a1g[g], B1, d);                               \
      f32x4 cx = *(const f32x4*)&coef[2048 + (U) * 64 + g * 16 + g16]; \
      f32x4 cy = *(const f32x4*)&coef[3072 + (U) * 64 + g * 16 + g16]; \
      f32x4 cz = *(const f32x4*)&coef[4096 + (U) * 64 + g * 16 + g16]; \
      _Pragma("unroll")                                              \
      for (int r = 0; r < 4; ++r) {                                  \
        mx[g][r] += cx[r] * v[r];                                    \
        my[g][r] += cy[r] * v[r];                                    \
        mz[g][r] += cz[r] * v[r];                                    \
      }                                                              \
    }                                                                \
  }

#define W3_TILE(U)                                                   \
  {                                                                  \
    const short* wb = W3P + ((80 + (U)) << 10) + (l << 3);           \
    bf16x8 B0 = *(const bf16x8*)wb;                                  \
    bf16x8 B1 = *(const bf16x8*)(wb + 512);                          \
    float bb = b3[((80 + (U)) << 4) + lr];                           \
    _Pragma("unroll")                                                \
    for (int g = 0; g < 4; ++g) {                                    \
      f32x4 d = {bb, bb, bb, bb};                                    \
      d = MFMA16(a0g[g], B0, d);                                     \
      f32x4 v = MFMA16(a1g[g], B1, d);                               \
      f32x4 c = *(const f32x4*)&coef[(U) * 64 + g * 16 + g16];       \
      _Pragma("unroll")                                              \
      for (int r = 0; r < 4; ++r) t3[g][r] += c[r] * v[r];           \
    }                                                                \
  }

  if (wid < 2) {
    // ---- m0 waves ----
    f32x4 acc0[4], acc1[4];
#pragma unroll
    for (int g = 0; g < 4; ++g) {
      acc0[g] = (f32x4){0, 0, 0, 0};
      acc1[g] = (f32x4){0, 0, 0, 0};
    }
    if (wid == 0) {
#pragma unroll 2
      for (int u = 0; u < 24; ++u) M0_PAIR(2 * u, u * 64);
#pragma unroll
      for (int g = 0; g < 4; ++g) {
        f32x4 y0v = *(const f32x4*)&y0s[g * 16 + g16];
#pragma unroll
        for (int r = 0; r < 4; ++r) { acc0[g][r] *= y0v[r]; acc1[g][r] *= y0v[r]; }
      }
    } else {
#pragma unroll 2
      for (int u = 24; u < 32; ++u) M0_PAIR(2 * u, u * 64);
#pragma unroll
      for (int g = 0; g < 4; ++g) {
        f32x4 y0v = *(const f32x4*)&y0s[g * 16 + g16];
#pragma unroll
        for (int r = 0; r < 4; ++r) { acc0[g][r] *= y0v[r]; acc1[g][r] *= y0v[r]; }
      }
#pragma unroll 2
      for (int p = 0; p < 16; ++p) M0_PAIR(112 + 2 * p, 5120 + p * 64);
    }
    // exchange: wid1 gives g0,g1 ; wid0 gives g2,g3
    __syncthreads();
    if (wid == 1) {
      float* p = scratch + l * 20;
      *(f32x4*)(p + 0) = acc0[0]; *(f32x4*)(p + 4) = acc1[0];
      *(f32x4*)(p + 8) = acc0[1]; *(f32x4*)(p + 12) = acc1[1];
    } else {
      float* p = scratch + 1280 + l * 20;
      *(f32x4*)(p + 0) = acc0[2]; *(f32x4*)(p + 4) = acc1[2];
      *(f32x4*)(p + 8) = acc0[3]; *(f32x4*)(p + 12) = acc1[3];
    }
    __syncthreads();
    const int gb = (wid == 0) ? 0 : 2;
    const float* p = (wid == 0) ? (scratch + l * 20) : (scratch + 1280 + l * 20);
    f32x4 t0 = *(const f32x4*)(p + 0), t1 = *(const f32x4*)(p + 4);
    f32x4 t2 = *(const f32x4*)(p + 8), t3_ = *(const f32x4*)(p + 12);
    i32x4 dd0 = *(const i32x4*)&dsts[(gb + 0) * 16 + g16];
    i32x4 dd1 = *(const i32x4*)&dsts[(gb + 1) * 16 + g16];
#pragma unroll
    for (int r = 0; r < 4; ++r) {
      float* base = agg + (long)dd0[r] * 80;
      atomicAdd(base + lr, acc0[gb + 0][r] + t0[r]);
      atomicAdd(base + 16 + lr, acc1[gb + 0][r] + t1[r]);
    }
#pragma unroll
    for (int r = 0; r < 4; ++r) {
      float* base = agg + (long)dd1[r] * 80;
      atomicAdd(base + lr, acc0[gb + 1][r] + t2[r]);
      atomicAdd(base + 16 + lr, acc1[gb + 1][r] + t3_[r]);
    }
  } else {
    // ---- m1 waves ----
    f32x4 mx[4], my[4], mz[4], t3[4];
#pragma unroll
    for (int g = 0; g < 4; ++g) {
      mx[g] = (f32x4){0, 0, 0, 0}; my[g] = (f32x4){0, 0, 0, 0};
      mz[g] = (f32x4){0, 0, 0, 0}; t3[g] = (f32x4){0, 0, 0, 0};
    }
    if (wid == 2) {
#pragma unroll 2
      for (int u = 0; u < 8; ++u) W2_TILE(u);
#pragma unroll 2
      for (int u = 0; u < 16; ++u) W3_TILE(u);
    } else {
#pragma unroll 2
      for (int u = 8; u < 16; ++u) W2_TILE(u);
#pragma unroll 2
      for (int u = 16; u < 32; ++u) W3_TILE(u);
    }
    // finalize: m = y0*m(w2) + y1*t3(w3)
#pragma unroll
    for (int g = 0; g < 4; ++g) {
      f32x4 y0v = *(const f32x4*)&y0s[g * 16 + g16];
      f32x4 yx = *(const f32x4*)&y1s[g * 16 + g16];
      f32x4 yy = *(const f32x4*)&y1s[64 + g * 16 + g16];
      f32x4 yz = *(const f32x4*)&y1s[128 + g * 16 + g16];
#pragma unroll
      for (int r = 0; r < 4; ++r) {
        mx[g][r] = mx[g][r] * y0v[r] + yx[r] * t3[g][r];
        my[g][r] = my[g][r] * y0v[r] + yy[r] * t3[g][r];
        mz[g][r] = mz[g][r] * y0v[r] + yz[r] * t3[g][r];
      }
    }
    // exchange: wid3 gives g0,g1 ; wid2 gives g2,g3
    __syncthreads();
    if (wid == 3) {
      float* p = scratch + 2560 + l * 28;
      *(f32x4*)(p + 0) = mx[0]; *(f32x4*)(p + 4) = my[0]; *(f32x4*)(p + 8) = mz[0];
      *(f32x4*)(p + 12) = mx[1]; *(f32x4*)(p + 16) = my[1]; *(f32x4*)(p + 20) = mz[1];
    } else {
      float* p = scratch + 4352 + l * 28;
      *(f32x4*)(p + 0) = mx[2]; *(f32x4*)(p + 4) = my[2]; *(f32x4*)(p + 8) = mz[2];
      *(f32x4*)(p + 12) = mx[3]; *(f32x4*)(p + 16) = my[3]; *(f32x4*)(p + 20) = mz[3];
    }
    __syncthreads();
    const int gb = (wid == 2) ? 0 : 2;
    const float* p = (wid == 2) ? (scratch + 2560 + l * 28) : (scratch + 4352 + l * 28);
    f32x4 u0 = *(const f32x4*)(p + 0), u1 = *(const f32x4*)(p + 4);
    f32x4 u2 = *(const f32x4*)(p + 8), u3 = *(const f32x4*)(p + 12);
    f32x4 u4 = *(const f32x4*)(p + 16), u5 = *(const f32x4*)(p + 20);
    i32x4 dd0 = *(const i32x4*)&dsts[(gb + 0) * 16 + g16];
    i32x4 dd1 = *(const i32x4*)&dsts[(gb + 1) * 16 + g16];
#pragma unroll
    for (int r = 0; r < 4; ++r) {
      float* base = agg + (long)dd0[r] * 80;
      atomicAdd(base + 32 + lr * 3 + 0, mx[gb + 0][r] + u0[r]);
      atomicAdd(base + 32 + lr * 3 + 1, my[gb + 0][r] + u1[r]);
      atomicAdd(base + 32 + lr * 3 + 2, mz[gb + 0][r] + u2[r]);
    }
#pragma unroll
    for (int r = 0; r < 4; ++r) {
      float* base = agg + (long)dd1[r] * 80;
      atomicAdd(base + 32 + lr * 3 + 0, mx[gb + 1][r] + u3[r]);
      atomicAdd(base + 32 + lr * 3 + 1, my[gb + 1][r] + u4[r]);
      atomicAdd(base + 32 + lr * 3 + 2, mz[gb + 1][r] + u5[r]);
    }
  }
  if (tid < 64) atomicAdd(cnt + dsts[tid], 1.0f);
#undef M0_PAIR
#undef W2_TILE
#undef W3_TILE
}

// ---- node_a: wave-per-node (16 nodes/block), lane-mapped 80-wide output ----
// lane l<32: out[l]=x0[l]; 32<=l<64: out[l]=x1[l-32]; l<16 also out[64+l]=x1[32+l].
__global__ __launch_bounds__(256) void node_a(
    const float* __restrict__ h, const float* __restrict__ A0,
    const float* __restrict__ A1p, const float* __restrict__ agg,
    const float* __restrict__ cnt, float* __restrict__ outpre,
    float* __restrict__ stats) {
  __shared__ float A0s[1024], A1ps[256], red[80];
  const int tid = threadIdx.x;
  for (int i = tid; i < 1280; i += 256) {
    if (i < 1024) A0s[i] = A0[i];
    else A1ps[i - 1024] = A1p[i - 1024];
  }
  if (tid < 80) red[tid] = 0.f;
  __syncthreads();
  const int wid = tid >> 6, l = tid & 63;

  // per-lane fixed stat-slot partials across the 4 nodes
  float s1 = 0.f, s2 = 0.f, s3 = 0.f;

  // precompute lane mapping
  const int jA = l - 32;              // valid for l>=32
  const int wA = (l >= 32) ? jA / 3 : 0;
  const int iA = (l >= 32) ? jA - wA * 3 : 0;
  const int jB = 32 + l;              // valid for l<16
  const int wB = jB / 3;
  const int iB = jB - wB * 3;

#pragma unroll 1
  for (int it = 0; it < 4; ++it) {
    const int n = blockIdx.x * 16 + wid * 4 + it;   // 10000 = 625*16 exact
    const float* hr = h + (long)n * 80;
    const float* ar = agg + (long)n * 80;
    const float inv = 1.f / fmaxf(cnt[n], 1.f);
    float valA;
    if (l < 32) {
      float x = 0.f;
#pragma unroll 8
      for (int u = 0; u < 32; ++u) x += hr[u] * A0s[u * 32 + l];
      valA = x * INV_SQRT_M0 + ar[l] * inv;
    } else {
      float x = 0.f;
#pragma unroll 8
      for (int u = 0; u < 16; ++u) x += hr[32 + u * 3 + iA] * A1ps[u * 16 + wA];
      valA = x * INV_SQRT_M1 + ar[l] * inv;
    }
    float valB = 0.f;
    if (l < 16) {
      float x = 0.f;
#pragma unroll 8
      for (int u = 0; u < 16; ++u) x += hr[32 + u * 3 + iB] * A1ps[u * 16 + wB];
      valB = x * INV_SQRT_M1 + ar[64 + l] * inv;
    }
    outpre[(long)n * 80 + l] = valA;
    if (l < 16) outpre[(long)n * 80 + 64 + l] = valB;
    if (l < 32) { s1 += valA; s2 += valA * valA; }
    else s2 += valA * valA;
    if (l < 16) s3 += valB * valB;
  }

  // lane -> stat slot (fixed): l<32 -> red[l], red[32+l]; l>=32 -> red[64+wA]; valB -> red[64+wB]
  if (l < 32) {
    atomicAdd(&red[l], s1);
    atomicAdd(&red[32 + l], s2);
  } else {
    atomicAdd(&red[64 + wA], s2);
  }
  if (l < 16) atomicAdd(&red[64 + wB], s3);
  __syncthreads();
  if (tid < 80) atomicAdd(&stats[tid], red[tid]);
}

__global__ void node_b(const float* __restrict__ outpre, const float* __restrict__ stats,
                       const float* __restrict__ bnw0, const float* __restrict__ bnb0,
                       const float* __restrict__ bnw1, const float* __restrict__ h,
                       float* __restrict__ out) {
  int idx = blockIdx.x * 256 + threadIdx.x;
  if (idx >= NN * 80) return;
  int c = idx % 80;
  float v = outpre[idx];
  const float invN = 1.f / NN;
  float o;
  if (c < 32) {
    float mu = stats[c] * invN;
    float var = stats[32 + c] * invN - mu * mu;
    o = (v - mu) * rsqrtf(var + EPSV) * bnw0[c] + bnb0[c];
  } else {
    int u = (c - 32) / 3;
    float nr = stats[64 + u] * invN;
    o = v * rsqrtf(nr + EPSV) * bnw1[u];
  }
  out[idx] = o + h[idx];
}

extern "C" void kernel_launch(void* const* d_in, const int* in_sizes, int n_in,
                              void* d_out, int out_size, void* d_ws, size_t ws_size,
                              hipStream_t stream) {
  const float* h    = (const float*)d_in[0];
  const int*   eidx = (const int*)d_in[1];
  const float* esh  = (const float*)d_in[2];
  const float* ef   = (const float*)d_in[3];
  const float* W1   = (const float*)d_in[4];
  const float* b1   = (const float*)d_in[5];
  const float* W2   = (const float*)d_in[6];
  const float* b2   = (const float*)d_in[7];
  const float* W3   = (const float*)d_in[8];
  const float* b3   = (const float*)d_in[9];
  const float* A0   = (const float*)d_in[10];
  const float* A1p  = (const float*)d_in[11];
  const float* bnw0 = (const float*)d_in[12];
  const float* bnb0 = (const float*)d_in[13];
  const float* bnw1 = (const float*)d_in[14];
  float* out = (float*)d_out;

  float* ws = (float*)d_ws;
  float* agg    = ws;             // 800000
  float* cnt    = ws + 800000;    // 10000
  float* stats  = ws + 810000;    // 80
  float* outpre = ws + 810080;    // 800000
  short* W3P    = (short*)(ws + 1610080);  // 147456 shorts
  short* W1P    = W3P + WNUM * 64;         // 4096 shorts
  short* W2P    = W1P + 4096;              // 4096 shorts

  hipMemsetAsync(agg, 0, (size_t)810080 * sizeof(float), stream);

  prep_weights<<<(WNUM * 64 + 8192 + 255) / 256, 256, 0, stream>>>(W1, W2, W3, W1P,
                                                                   W2P, W3P);
  edge_kernel<<<NE / 64, 256, 0, stream>>>(h, eidx, esh, ef, W1P, b1, W2P, b2, W3P, b3,
                                           agg, cnt);
  node_a<<<NN / 16, 256, 0, stream>>>(h, A0, A1p, agg, cnt, outpre, stats);
  node_b<<<(NN * 80 + 255) / 256, 256, 0, stream>>>(outpre, stats, bnw0, bnb0, bnw1, h,
                                                    out);
}